// Round 6
// baseline (85.221 us; speedup 1.0000x reference)
//
#include <hip/hip_runtime.h>
#include <math.h>

#define HH 2048
#define WW 2048
#define HWFULL (HH*WW)

typedef float v4f __attribute__((ext_vector_type(4)));
union F4 { float4 v; v4f c; float f[4]; };

// ---------------- K1: ds9 (9,128,128) bilinear AC downsample  +  guide at 64x64 ----------------
__global__ __launch_bounds__(256) void k_ds9_guide(
        const float* __restrict__ low, const float* __restrict__ med,
        const float* __restrict__ high,
        const float* __restrict__ gw1, const float* __restrict__ gb1,
        const float* __restrict__ gamma, const float* __restrict__ beta,
        const float* __restrict__ mean, const float* __restrict__ var,
        const float* __restrict__ gw2, const float* __restrict__ gb2,
        float* __restrict__ ds9, float* __restrict__ guideb) {
    int idx = blockIdx.x * 256 + threadIdx.x;      // 0..151551
    if (idx < 147456) {
        int ch = idx >> 14;
        int rem = idx & 16383;
        int oy = rem >> 7, ox = rem & 127;
        const float* base = (ch < 3) ? low : (ch < 6 ? med : high);
        const float* p = base + (ch % 3) * HWFULL;
        float ysf = oy * (2047.0f / 127.0f);
        int y0 = (int)ysf; if (y0 > 2047) y0 = 2047;
        int y1 = y0 + 1;   if (y1 > 2047) y1 = 2047;
        float wy = ysf - (float)y0;
        float xsf = ox * (2047.0f / 127.0f);
        int x0 = (int)xsf; if (x0 > 2047) x0 = 2047;
        int x1 = x0 + 1;   if (x1 > 2047) x1 = 2047;
        float wx = xsf - (float)x0;
        float t = p[y0 * WW + x0] * (1.0f - wx) + p[y0 * WW + x1] * wx;
        float b = p[y1 * WW + x0] * (1.0f - wx) + p[y1 * WW + x1] * wx;
        ds9[idx] = t * (1.0f - wy) + b * wy;
    } else {
        int g = idx - 147456;                      // 0..4095
        int h = g >> 6, w = g & 63;
        float ysf = h * (2047.0f / 63.0f);
        int y0 = (int)ysf; if (y0 > 2047) y0 = 2047;
        int y1 = y0 + 1;   if (y1 > 2047) y1 = 2047;
        float wy = ysf - (float)y0;
        float xsf = w * (2047.0f / 63.0f);
        int x0 = (int)xsf; if (x0 > 2047) x0 = 2047;
        int x1 = x0 + 1;   if (x1 > 2047) x1 = 2047;
        float wx = xsf - (float)x0;
        int yy[2] = { y0, y1 };
        int xx[2] = { x0, x1 };
        float gp[2][2];
        #pragma unroll
        for (int a = 0; a < 2; ++a) {
            #pragma unroll
            for (int bb = 0; bb < 2; ++bb) {
                int pix = yy[a] * WW + xx[bb];
                float i0 = 0.33f * (low[pix]            + med[pix]            + high[pix]);
                float i1 = 0.33f * (low[HWFULL + pix]   + med[HWFULL + pix]   + high[HWFULL + pix]);
                float i2 = 0.33f * (low[2*HWFULL + pix] + med[2*HWFULL + pix] + high[2*HWFULL + pix]);
                float acc = gb2[0];
                for (int k = 0; k < 16; ++k) {
                    float t = gb1[k] + gw1[k*3] * i0 + gw1[k*3+1] * i1 + gw1[k*3+2] * i2;
                    t = gamma[k] * (t - mean[k]) * (1.0f / sqrtf(var[k] + 1e-5f)) + beta[k];
                    t = fmaxf(t, 0.0f);
                    acc += gw2[k] * t;
                }
                gp[a][bb] = 1.0f / (1.0f + expf(-acc));
            }
        }
        guideb[g] = (1.0f - wy) * ((1.0f - wx) * gp[0][0] + wx * gp[0][1])
                  +         wy  * ((1.0f - wx) * gp[1][0] + wx * gp[1][1]);
    }
}

// ---------------- K2: conv1 9->16 3x3 s2 p1 relu: (9,128,128)->(16,64,64). 4 blocks / out row ----
__global__ __launch_bounds__(256) void k_conv1(const float* __restrict__ in,
                                               const float* __restrict__ w,
                                               const float* __restrict__ b,
                                               float* __restrict__ out) {
    __shared__ float sd[9 * 3 * 34];               // [ci][r][j], ix = 32q-1+j, j<33
    const int oy = blockIdx.x >> 2;                // 0..63
    const int q  = blockIdx.x & 3;
    const int tid = threadIdx.x;
    for (int idx = tid; idx < 9 * 3 * 33; idx += 256) {
        int ch = idx / 99;
        int rem = idx - 99 * ch;
        int r = rem / 33;
        int j = rem - 33 * r;
        int x = 32 * q - 1 + j;
        int iy = 2 * oy - 1 + r;
        sd[(ch * 3 + r) * 34 + j] =
            (x >= 0 && x < 128 && iy >= 0 && iy < 128) ? in[ch * 16384 + iy * 128 + x] : 0.0f;
    }
    __syncthreads();
    int co = tid >> 4, xl = tid & 15;
    float acc = b[co];
    for (int ci = 0; ci < 9; ++ci) {
        #pragma unroll
        for (int ky = 0; ky < 3; ++ky) {
            const float* wr = w + ((co * 9 + ci) * 3 + ky) * 3;
            const float* row = &sd[(ci * 3 + ky) * 34 + 2 * xl];
            acc += wr[0] * row[0] + wr[1] * row[1] + wr[2] * row[2];
        }
    }
    out[co * 4096 + oy * 64 + 16 * q + xl] = fmaxf(acc, 0.0f);
}

// ---------------- K3: conv2 16->32: (16,64,64)->(32,32,32). 4 blocks / out row ----------------
__global__ __launch_bounds__(256) void k_conv2(const float* __restrict__ in,
                                               const float* __restrict__ w,
                                               const float* __restrict__ b,
                                               float* __restrict__ out) {
    __shared__ float sd[16 * 3 * 18];              // [ci][r][j], ix = 16q-1+j, j<17
    const int oy = blockIdx.x >> 2;                // 0..31
    const int q  = blockIdx.x & 3;
    const int tid = threadIdx.x;
    for (int idx = tid; idx < 16 * 3 * 17; idx += 256) {
        int ch = idx / 51;
        int rem = idx - 51 * ch;
        int r = rem / 17;
        int j = rem - 17 * r;
        int x = 16 * q - 1 + j;
        int iy = 2 * oy - 1 + r;
        sd[(ch * 3 + r) * 18 + j] =
            (x >= 0 && x < 64 && iy >= 0 && iy < 64) ? in[ch * 4096 + iy * 64 + x] : 0.0f;
    }
    __syncthreads();
    int co = tid >> 3, xl = tid & 7;
    float acc = b[co];
    for (int ci = 0; ci < 16; ++ci) {
        #pragma unroll
        for (int ky = 0; ky < 3; ++ky) {
            const float* wr = w + ((co * 16 + ci) * 3 + ky) * 3;
            const float* row = &sd[(ci * 3 + ky) * 18 + 2 * xl];
            acc += wr[0] * row[0] + wr[1] * row[1] + wr[2] * row[2];
        }
    }
    out[co * 1024 + oy * 32 + 8 * q + xl] = fmaxf(acc, 0.0f);
}

// ---------------- K4: conv3 (32->64 3x3 s2 relu) + conv4 (64->192 1x1). 4 blocks / out row ------
__global__ __launch_bounds__(256) void k_conv34(const float* __restrict__ in,
                                                const float* __restrict__ w3,
                                                const float* __restrict__ b3,
                                                const float* __restrict__ w4,
                                                const float* __restrict__ b4,
                                                float* __restrict__ gridvol) {
    __shared__ float sd[32 * 3 * 10];              // [ci][r][j], ix = 8q-1+j, j<9
    __shared__ float sc3[64 * 4];                  // [ci][px]
    const int oy = blockIdx.x >> 2;                // 0..15
    const int q  = blockIdx.x & 3;
    const int tid = threadIdx.x;
    for (int idx = tid; idx < 32 * 3 * 9; idx += 256) {
        int ch = idx / 27;
        int rem = idx - 27 * ch;
        int r = rem / 9;
        int j = rem - 9 * r;
        int x = 8 * q - 1 + j;
        int iy = 2 * oy - 1 + r;
        sd[(ch * 3 + r) * 10 + j] =
            (x >= 0 && x < 32 && iy >= 0 && iy < 32) ? in[ch * 1024 + iy * 32 + x] : 0.0f;
    }
    __syncthreads();
    {   // conv3: 64 ch x 4 px = 256 outputs, 1 per thread
        int co = tid >> 2, xl = tid & 3;
        float acc = b3[co];
        for (int ci = 0; ci < 32; ++ci) {
            #pragma unroll
            for (int ky = 0; ky < 3; ++ky) {
                const float* wr = w3 + ((co * 32 + ci) * 3 + ky) * 3;
                const float* row = &sd[(ci * 3 + ky) * 10 + 2 * xl];
                acc += wr[0] * row[0] + wr[1] * row[1] + wr[2] * row[2];
            }
        }
        sc3[co * 4 + xl] = fmaxf(acc, 0.0f);
    }
    __syncthreads();
    {   // conv4: 192 out-ch x 4 px = 768 outputs, 3 per thread
        int px = tid & 3;
        int ob = tid >> 2;                         // 0..63
        #pragma unroll
        for (int k = 0; k < 3; ++k) {
            int o = ob + 64 * k;                   // 0..191
            float sum = b4[o];
            const float* wp = w4 + o * 64;
            for (int i = 0; i < 64; ++i)
                sum += wp[i] * sc3[i * 4 + px];
            gridvol[o * 256 + oy * 16 + 4 * q + px] = sum;
        }
    }
}

// ---------------- K5: slice + y-lerp -> ab_full[2048][64*12]. 256 blocks x 8 rows ----------------
__global__ __launch_bounds__(256) void k_slice_ab(
        const float* __restrict__ gridvol, const float* __restrict__ guideb,
        float* __restrict__ ab_full) {
    __shared__ float s[3 * 64 * 12];               // sct rows v0, v0+1, v0+2 (clamped)
    const int b = blockIdx.x;                      // 0..255, rows [8b, 8b+8)
    const int tid = threadIdx.x;
    float byf = (8 * b) * (63.0f / 2047.0f);
    int v0 = (int)byf; if (v0 > 63) v0 = 63;

    if (tid < 192) {
        int rr = tid >> 6, x = tid & 63;
        int srow = v0 + rr; if (srow > 63) srow = 63;
        float guide = guideb[srow * 64 + x];
        float hg = srow * (2.0f / 63.0f) - 1.0f;
        float wg = x * (2.0f / 63.0f) - 1.0f;
        float ix = ((guide + 1.0f) * 16.0f - 1.0f) * 0.5f;
        float iy = ((hg    + 1.0f) * 16.0f - 1.0f) * 0.5f;
        float iz = ((wg    + 1.0f) * 16.0f - 1.0f) * 0.5f;
        float xf = floorf(ix), yf = floorf(iy), zf = floorf(iz);
        float fx = ix - xf, fyy = iy - yf, fz = iz - zf;
        int xi = (int)xf, yi = (int)yf, zi = (int)zf;
        float scv[12];
        #pragma unroll
        for (int c = 0; c < 12; ++c) scv[c] = 0.0f;
        #pragma unroll
        for (int dz = 0; dz < 2; ++dz) {
            int z = zi + dz; float wz = dz ? fz : 1.0f - fz;
            if (z < 0 || z > 15) continue;
            #pragma unroll
            for (int dy = 0; dy < 2; ++dy) {
                int yv = yi + dy; float wyv = dy ? fyy : 1.0f - fyy;
                if (yv < 0 || yv > 15) continue;
                #pragma unroll
                for (int dx = 0; dx < 2; ++dx) {
                    int xv = xi + dx; float wxv = dx ? fx : 1.0f - fx;
                    if (xv < 0 || xv > 15) continue;
                    float wgt = wz * wyv * wxv;
                    int base = yv * 16 + xv;
                    #pragma unroll
                    for (int c = 0; c < 12; ++c)
                        scv[c] += wgt * gridvol[(c * 16 + z) * 256 + base];
                }
            }
        }
        #pragma unroll
        for (int c = 0; c < 12; ++c) s[(rr * 64 + x) * 12 + c] = scv[c];
    }
    __syncthreads();

    #pragma unroll
    for (int k = 0; k < 24; ++k) {
        int e = k * 256 + tid;                     // 0..6143
        int r8 = e / 768;
        int rem = e - 768 * r8;
        int x = rem / 12;
        int c = rem - 12 * x;
        int y = 8 * b + r8;
        float iyf = y * (63.0f / 2047.0f);
        int y0 = (int)iyf; if (y0 > 63) y0 = 63;
        int y1 = y0 + 1;   if (y1 > 63) y1 = 63;
        float fy = iyf - (float)y0;
        int i0 = y0 - v0, i1 = y1 - v0;
        float t = s[(i0 * 64 + x) * 12 + c];
        float bo = s[(i1 * 64 + x) * 12 + c];
        ab_full[y * 768 + rem] = t + (bo - t) * fy;
    }
}

// ---------------- K6: apply. 2048 blocks (1 per row), 8 px/thread, deep MLP ----------------
__global__ __launch_bounds__(256) void k_apply(
        const float* __restrict__ low, const float* __restrict__ med,
        const float* __restrict__ high, const float* __restrict__ ab_full,
        float* __restrict__ out) {
    __shared__ F4 abs4[192];                       // this row's 64*12 coefficients
    const int y = blockIdx.x;
    const int tid = threadIdx.x;
    const int HW4 = HWFULL / 4;
    const int base = y << 9;

    const float4* Lp = (const float4*)low;
    const float4* Mp = (const float4*)med;
    const float4* Hp = (const float4*)high;

    // issue all 18 input loads up front; latency hides the ab staging + barrier
    F4 L[2][3], M[2][3], Hh[2][3];
    #pragma unroll
    for (int q = 0; q < 2; ++q) {
        int vi = base + tid + q * 256;
        L[q][0].v = Lp[vi]; L[q][1].v = Lp[vi + HW4]; L[q][2].v = Lp[vi + 2 * HW4];
        M[q][0].v = Mp[vi]; M[q][1].v = Mp[vi + HW4]; M[q][2].v = Mp[vi + 2 * HW4];
        Hh[q][0].v = Hp[vi]; Hh[q][1].v = Hp[vi + HW4]; Hh[q][2].v = Hp[vi + 2 * HW4];
    }

    if (tid < 192)
        abs4[tid].v = ((const float4*)(ab_full + y * 768))[tid];
    __syncthreads();

    float4* Op = (float4*)out;
    #pragma unroll
    for (int q = 0; q < 2; ++q) {
        int v = tid + q * 256;                     // float4 column 0..511
        int vi = base + v;
        // dual-cell coefficient fetch: cells f and (maybe) f+1 cover px 4v..4v+3
        int x_first = v << 2;
        float ixf0 = x_first * (63.0f / 2047.0f);
        int f = (int)ixf0; if (f > 63) f = 63;
        float ixf3 = (x_first + 3) * (63.0f / 2047.0f);
        int s3 = (int)ixf3; if (s3 > 63) s3 = 63;
        int fp1 = f + 1;  if (fp1 > 63) fp1 = 63;
        int sp1 = s3 + 1; if (sp1 > 63) sp1 = 63;
        F4 A0[3], B0[3], C0[3];
        #pragma unroll
        for (int qq = 0; qq < 3; ++qq) {
            A0[qq] = abs4[f   * 3 + qq];
            B0[qq] = abs4[fp1 * 3 + qq];
            C0[qq] = abs4[sp1 * 3 + qq];
        }

        F4 o0, o1, o2;
        #pragma unroll
        for (int p = 0; p < 4; ++p) {
            int x = x_first + p;
            float ixf = x * (63.0f / 2047.0f);
            int x0 = (int)ixf; if (x0 > 63) x0 = 63;
            float fx = ixf - (float)x0;
            bool first = (x0 == f);
            float im0 = 0.33f * (L[q][0].f[p] + M[q][0].f[p] + Hh[q][0].f[p]);
            float im1 = 0.33f * (L[q][1].f[p] + M[q][1].f[p] + Hh[q][1].f[p]);
            float im2 = 0.33f * (L[q][2].f[p] + M[q][2].f[p] + Hh[q][2].f[p]);
            float cf[12];
            #pragma unroll
            for (int qq = 0; qq < 3; ++qq) {
                #pragma unroll
                for (int r = 0; r < 4; ++r) {
                    float a = first ? A0[qq].f[r] : B0[qq].f[r];
                    float bb = first ? B0[qq].f[r] : C0[qq].f[r];
                    cf[qq * 4 + r] = a + (bb - a) * fx;
                }
            }
            o0.f[p] = cf[0] * im0 + cf[1]  * im1 + cf[2]  * im2 + cf[3];
            o1.f[p] = cf[4] * im0 + cf[5]  * im1 + cf[6]  * im2 + cf[7];
            o2.f[p] = cf[8] * im0 + cf[9]  * im1 + cf[10] * im2 + cf[11];
        }
        Op[vi]           = o0.v;
        Op[vi + HW4]     = o1.v;
        Op[vi + 2 * HW4] = o2.v;
    }
}

extern "C" void kernel_launch(void* const* d_in, const int* in_sizes, int n_in,
                              void* d_out, int out_size, void* d_ws, size_t ws_size,
                              hipStream_t stream) {
    const float* low   = (const float*)d_in[0];
    const float* med   = (const float*)d_in[1];
    const float* high  = (const float*)d_in[2];
    const float* w1    = (const float*)d_in[3];
    const float* b1    = (const float*)d_in[4];
    const float* w2    = (const float*)d_in[5];
    const float* b2    = (const float*)d_in[6];
    const float* w3    = (const float*)d_in[7];
    const float* b3    = (const float*)d_in[8];
    const float* w4    = (const float*)d_in[9];
    const float* b4    = (const float*)d_in[10];
    const float* gw1   = (const float*)d_in[11];
    const float* gb1   = (const float*)d_in[12];
    const float* gamma = (const float*)d_in[13];
    const float* beta  = (const float*)d_in[14];
    const float* mean  = (const float*)d_in[15];
    const float* var   = (const float*)d_in[16];
    const float* gw2   = (const float*)d_in[17];
    const float* gb2   = (const float*)d_in[18];
    float* out = (float*)d_out;

    float* ws      = (float*)d_ws;
    float* ab_full = ws;                    // 2048*768 = 1572864
    float* ds9     = ab_full + 1572864;     //  9*128*128 = 147456
    float* c1      = ds9 + 147456;          // 16*64*64   =  65536
    float* c2v     = c1 + 65536;            // 32*32*32   =  32768
    float* gridvol = c2v + 32768;           // 192*16*16  =  49152
    float* guideb  = gridvol + 49152;       // 64*64      =   4096

    hipLaunchKernelGGL(k_ds9_guide, dim3(592), dim3(256), 0, stream,
                       low, med, high, gw1, gb1, gamma, beta, mean, var, gw2, gb2,
                       ds9, guideb);
    hipLaunchKernelGGL(k_conv1,    dim3(256), dim3(256), 0, stream, ds9, w1, b1, c1);
    hipLaunchKernelGGL(k_conv2,    dim3(128), dim3(256), 0, stream, c1, w2, b2, c2v);
    hipLaunchKernelGGL(k_conv34,   dim3(64),  dim3(256), 0, stream, c2v, w3, b3, w4, b4, gridvol);
    hipLaunchKernelGGL(k_slice_ab, dim3(256), dim3(256), 0, stream, gridvol, guideb, ab_full);
    hipLaunchKernelGGL(k_apply,    dim3(2048), dim3(256), 0, stream, low, med, high, ab_full, out);
}

// Round 7
// 81.202 us; speedup vs baseline: 1.0495x; 1.0495x over previous
//
#include <hip/hip_runtime.h>
#include <math.h>

#define HH 2048
#define WW 2048
#define HWFULL (HH*WW)

typedef float v4f __attribute__((ext_vector_type(4)));
union F4 { float4 v; v4f c; float f[4]; };

// ---------------- K1: conv1 9->16 3x3 s2 p1 relu, ds9 bilinear computed inline ----------------
// output (16,64,64); 4 blocks per output row, 32-px chunk each
__global__ __launch_bounds__(256) void k_conv1(const float* __restrict__ low,
                                               const float* __restrict__ med,
                                               const float* __restrict__ high,
                                               const float* __restrict__ w,
                                               const float* __restrict__ b,
                                               float* __restrict__ out) {
    __shared__ float sd[9 * 3 * 34];               // [ci][r][j], ix128 = 32q-1+j, j<33
    const int oy = blockIdx.x >> 2;                // 0..63
    const int q  = blockIdx.x & 3;
    const int tid = threadIdx.x;
    for (int idx = tid; idx < 9 * 3 * 33; idx += 256) {
        int ch = idx / 99;
        int rem = idx - 99 * ch;
        int r = rem / 33;
        int j = rem - 33 * r;
        int ix128 = 32 * q - 1 + j;
        int iy128 = 2 * oy - 1 + r;
        float val = 0.0f;
        if (ix128 >= 0 && ix128 < 128 && iy128 >= 0 && iy128 < 128) {
            const float* base = (ch < 3) ? low : (ch < 6 ? med : high);
            const float* p = base + (ch % 3) * HWFULL;
            float ysf = iy128 * (2047.0f / 127.0f);
            int y0 = (int)ysf; if (y0 > 2047) y0 = 2047;
            int y1 = y0 + 1;   if (y1 > 2047) y1 = 2047;
            float wy = ysf - (float)y0;
            float xsf = ix128 * (2047.0f / 127.0f);
            int x0 = (int)xsf; if (x0 > 2047) x0 = 2047;
            int x1 = x0 + 1;   if (x1 > 2047) x1 = 2047;
            float wx = xsf - (float)x0;
            float t = p[y0 * WW + x0] * (1.0f - wx) + p[y0 * WW + x1] * wx;
            float bo = p[y1 * WW + x0] * (1.0f - wx) + p[y1 * WW + x1] * wx;
            val = t * (1.0f - wy) + bo * wy;
        }
        sd[(ch * 3 + r) * 34 + j] = val;
    }
    __syncthreads();
    int co = tid >> 4, xl = tid & 15;
    float acc = b[co];
    for (int ci = 0; ci < 9; ++ci) {
        #pragma unroll
        for (int ky = 0; ky < 3; ++ky) {
            const float* wr = w + ((co * 9 + ci) * 3 + ky) * 3;
            const float* row = &sd[(ci * 3 + ky) * 34 + 2 * xl];
            acc += wr[0] * row[0] + wr[1] * row[1] + wr[2] * row[2];
        }
    }
    out[co * 4096 + oy * 64 + 16 * q + xl] = fmaxf(acc, 0.0f);
}

// ---------------- K2: conv2 16->32 (16,64,64)->(32,32,32)  +  guide side-job ----------------
__global__ __launch_bounds__(256) void k_conv2(const float* __restrict__ in,
                                               const float* __restrict__ w,
                                               const float* __restrict__ b,
                                               const float* __restrict__ low,
                                               const float* __restrict__ med,
                                               const float* __restrict__ high,
                                               const float* __restrict__ gw1, const float* __restrict__ gb1,
                                               const float* __restrict__ gamma, const float* __restrict__ beta,
                                               const float* __restrict__ mean, const float* __restrict__ var,
                                               const float* __restrict__ gw2, const float* __restrict__ gb2,
                                               float* __restrict__ out,
                                               float* __restrict__ guideb) {
    __shared__ float sd[16 * 3 * 18];              // [ci][r][j], ix = 16q-1+j, j<17
    const int oy = blockIdx.x >> 2;                // 0..31
    const int q  = blockIdx.x & 3;
    const int tid = threadIdx.x;
    for (int idx = tid; idx < 16 * 3 * 17; idx += 256) {
        int ch = idx / 51;
        int rem = idx - 51 * ch;
        int r = rem / 17;
        int j = rem - 17 * r;
        int x = 16 * q - 1 + j;
        int iy = 2 * oy - 1 + r;
        sd[(ch * 3 + r) * 18 + j] =
            (x >= 0 && x < 64 && iy >= 0 && iy < 64) ? in[ch * 4096 + iy * 64 + x] : 0.0f;
    }
    __syncthreads();
    int co = tid >> 3, xl = tid & 7;
    float acc = b[co];
    for (int ci = 0; ci < 16; ++ci) {
        #pragma unroll
        for (int ky = 0; ky < 3; ++ky) {
            const float* wr = w + ((co * 16 + ci) * 3 + ky) * 3;
            const float* row = &sd[(ci * 3 + ky) * 18 + 2 * xl];
            acc += wr[0] * row[0] + wr[1] * row[1] + wr[2] * row[2];
        }
    }
    out[co * 1024 + oy * 32 + 8 * q + xl] = fmaxf(acc, 0.0f);

    // guide side-job: 128 blocks x 32 threads = 4096 guide samples (independent work)
    if (tid < 32) {
        int g = blockIdx.x * 32 + tid;             // 0..4095
        int h = g >> 6, wv = g & 63;
        float ysf = h * (2047.0f / 63.0f);
        int y0 = (int)ysf; if (y0 > 2047) y0 = 2047;
        int y1 = y0 + 1;   if (y1 > 2047) y1 = 2047;
        float wy = ysf - (float)y0;
        float xsf = wv * (2047.0f / 63.0f);
        int x0 = (int)xsf; if (x0 > 2047) x0 = 2047;
        int x1 = x0 + 1;   if (x1 > 2047) x1 = 2047;
        float wx = xsf - (float)x0;
        int yy[2] = { y0, y1 };
        int xx[2] = { x0, x1 };
        float gp[2][2];
        #pragma unroll
        for (int a = 0; a < 2; ++a) {
            #pragma unroll
            for (int bb = 0; bb < 2; ++bb) {
                int pix = yy[a] * WW + xx[bb];
                float i0 = 0.33f * (low[pix]            + med[pix]            + high[pix]);
                float i1 = 0.33f * (low[HWFULL + pix]   + med[HWFULL + pix]   + high[HWFULL + pix]);
                float i2 = 0.33f * (low[2*HWFULL + pix] + med[2*HWFULL + pix] + high[2*HWFULL + pix]);
                float acc2 = gb2[0];
                for (int k = 0; k < 16; ++k) {
                    float t = gb1[k] + gw1[k*3] * i0 + gw1[k*3+1] * i1 + gw1[k*3+2] * i2;
                    t = gamma[k] * (t - mean[k]) * (1.0f / sqrtf(var[k] + 1e-5f)) + beta[k];
                    t = fmaxf(t, 0.0f);
                    acc2 += gw2[k] * t;
                }
                gp[a][bb] = 1.0f / (1.0f + expf(-acc2));
            }
        }
        guideb[g] = (1.0f - wy) * ((1.0f - wx) * gp[0][0] + wx * gp[0][1])
                  +         wy  * ((1.0f - wx) * gp[1][0] + wx * gp[1][1]);
    }
}

// ---------------- K3: conv3 (32->64 3x3 s2 relu) + conv4 (64->192 1x1). 4 blocks / out row ------
__global__ __launch_bounds__(256) void k_conv34(const float* __restrict__ in,
                                                const float* __restrict__ w3,
                                                const float* __restrict__ b3,
                                                const float* __restrict__ w4,
                                                const float* __restrict__ b4,
                                                float* __restrict__ gridvol) {
    __shared__ float sd[32 * 3 * 10];              // [ci][r][j], ix = 8q-1+j, j<9
    __shared__ float sc3[64 * 4];                  // [ci][px]
    const int oy = blockIdx.x >> 2;                // 0..15
    const int q  = blockIdx.x & 3;
    const int tid = threadIdx.x;
    for (int idx = tid; idx < 32 * 3 * 9; idx += 256) {
        int ch = idx / 27;
        int rem = idx - 27 * ch;
        int r = rem / 9;
        int j = rem - 9 * r;
        int x = 8 * q - 1 + j;
        int iy = 2 * oy - 1 + r;
        sd[(ch * 3 + r) * 10 + j] =
            (x >= 0 && x < 32 && iy >= 0 && iy < 32) ? in[ch * 1024 + iy * 32 + x] : 0.0f;
    }
    __syncthreads();
    {   // conv3: 64 ch x 4 px = 256 outputs, 1 per thread
        int co = tid >> 2, xl = tid & 3;
        float acc = b3[co];
        for (int ci = 0; ci < 32; ++ci) {
            #pragma unroll
            for (int ky = 0; ky < 3; ++ky) {
                const float* wr = w3 + ((co * 32 + ci) * 3 + ky) * 3;
                const float* row = &sd[(ci * 3 + ky) * 10 + 2 * xl];
                acc += wr[0] * row[0] + wr[1] * row[1] + wr[2] * row[2];
            }
        }
        sc3[co * 4 + xl] = fmaxf(acc, 0.0f);
    }
    __syncthreads();
    {   // conv4: 192 out-ch x 4 px = 768 outputs, 3 per thread
        int px = tid & 3;
        int ob = tid >> 2;                         // 0..63
        #pragma unroll
        for (int k = 0; k < 3; ++k) {
            int o = ob + 64 * k;                   // 0..191
            float sum = b4[o];
            const float* wp = w4 + o * 64;
            for (int i = 0; i < 64; ++i)
                sum += wp[i] * sc3[i * 4 + px];
            gridvol[o * 256 + oy * 16 + 4 * q + px] = sum;
        }
    }
}

// ---------------- K4: slice + y-lerp -> ab_full[2048][64*12]. 256 blocks x 8 rows ----------------
__global__ __launch_bounds__(256) void k_slice_ab(
        const float* __restrict__ gridvol, const float* __restrict__ guideb,
        float* __restrict__ ab_full) {
    __shared__ float s[3 * 64 * 12];               // sct rows v0, v0+1, v0+2 (clamped)
    const int b = blockIdx.x;                      // 0..255, rows [8b, 8b+8)
    const int tid = threadIdx.x;
    float byf = (8 * b) * (63.0f / 2047.0f);
    int v0 = (int)byf; if (v0 > 63) v0 = 63;

    if (tid < 192) {
        int rr = tid >> 6, x = tid & 63;
        int srow = v0 + rr; if (srow > 63) srow = 63;
        float guide = guideb[srow * 64 + x];
        float hg = srow * (2.0f / 63.0f) - 1.0f;
        float wg = x * (2.0f / 63.0f) - 1.0f;
        float ix = ((guide + 1.0f) * 16.0f - 1.0f) * 0.5f;
        float iy = ((hg    + 1.0f) * 16.0f - 1.0f) * 0.5f;
        float iz = ((wg    + 1.0f) * 16.0f - 1.0f) * 0.5f;
        float xf = floorf(ix), yf = floorf(iy), zf = floorf(iz);
        float fx = ix - xf, fyy = iy - yf, fz = iz - zf;
        int xi = (int)xf, yi = (int)yf, zi = (int)zf;
        float scv[12];
        #pragma unroll
        for (int c = 0; c < 12; ++c) scv[c] = 0.0f;
        #pragma unroll
        for (int dz = 0; dz < 2; ++dz) {
            int z = zi + dz; float wz = dz ? fz : 1.0f - fz;
            if (z < 0 || z > 15) continue;
            #pragma unroll
            for (int dy = 0; dy < 2; ++dy) {
                int yv = yi + dy; float wyv = dy ? fyy : 1.0f - fyy;
                if (yv < 0 || yv > 15) continue;
                #pragma unroll
                for (int dx = 0; dx < 2; ++dx) {
                    int xv = xi + dx; float wxv = dx ? fx : 1.0f - fx;
                    if (xv < 0 || xv > 15) continue;
                    float wgt = wz * wyv * wxv;
                    int base = yv * 16 + xv;
                    #pragma unroll
                    for (int c = 0; c < 12; ++c)
                        scv[c] += wgt * gridvol[(c * 16 + z) * 256 + base];
                }
            }
        }
        #pragma unroll
        for (int c = 0; c < 12; ++c) s[(rr * 64 + x) * 12 + c] = scv[c];
    }
    __syncthreads();

    #pragma unroll
    for (int k = 0; k < 24; ++k) {
        int e = k * 256 + tid;                     // 0..6143
        int r8 = e / 768;
        int rem = e - 768 * r8;
        int x = rem / 12;
        int c = rem - 12 * x;
        int y = 8 * b + r8;
        float iyf = y * (63.0f / 2047.0f);
        int y0 = (int)iyf; if (y0 > 63) y0 = 63;
        int y1 = y0 + 1;   if (y1 > 63) y1 = 63;
        float fy = iyf - (float)y0;
        int i0 = y0 - v0, i1 = y1 - v0;
        float t = s[(i0 * 64 + x) * 12 + c];
        float bo = s[(i1 * 64 + x) * 12 + c];
        ab_full[y * 768 + rem] = t + (bo - t) * fy;
    }
}

// ---------------- K5: apply. Pure streaming: no LDS, no barrier. 4096 blocks, 4 px/thread -------
__global__ __launch_bounds__(256) void k_apply(
        const float* __restrict__ low, const float* __restrict__ med,
        const float* __restrict__ high, const float* __restrict__ ab_full,
        float* __restrict__ out) {
    const int g = blockIdx.x * 256 + threadIdx.x;  // float4 index 0..1048575
    const int y = g >> 9;
    const int v = g & 511;                         // float4 column 0..511
    const int HW4 = HWFULL / 4;

    const float4* Lp = (const float4*)low;
    const float4* Mp = (const float4*)med;
    const float4* Hp = (const float4*)high;

    // 9 input loads first
    F4 l0, l1, l2, m0, m1, m2, h0, h1, h2;
    l0.v = Lp[g]; l1.v = Lp[g + HW4]; l2.v = Lp[g + 2 * HW4];
    m0.v = Mp[g]; m1.v = Mp[g + HW4]; m2.v = Mp[g + 2 * HW4];
    h0.v = Hp[g]; h1.v = Hp[g + HW4]; h2.v = Hp[g + 2 * HW4];

    // 9 coefficient loads (L1-resident: whole block shares one 3 KB row)
    const float4* abr = (const float4*)(ab_full + y * 768);   // 192 x float4
    int x_first = v << 2;
    float ixf0 = x_first * (63.0f / 2047.0f);
    int f = (int)ixf0; if (f > 63) f = 63;
    float ixf3 = (x_first + 3) * (63.0f / 2047.0f);
    int s3 = (int)ixf3; if (s3 > 63) s3 = 63;
    int fp1 = f + 1;  if (fp1 > 63) fp1 = 63;
    int sp1 = s3 + 1; if (sp1 > 63) sp1 = 63;
    F4 A0[3], B0[3], C0[3];
    #pragma unroll
    for (int qq = 0; qq < 3; ++qq) {
        A0[qq].v = abr[f   * 3 + qq];
        B0[qq].v = abr[fp1 * 3 + qq];
        C0[qq].v = abr[sp1 * 3 + qq];
    }

    F4 o0, o1, o2;
    #pragma unroll
    for (int p = 0; p < 4; ++p) {
        int x = x_first + p;
        float ixf = x * (63.0f / 2047.0f);
        int x0 = (int)ixf; if (x0 > 63) x0 = 63;
        float fx = ixf - (float)x0;
        bool first = (x0 == f);
        float im0 = 0.33f * (l0.f[p] + m0.f[p] + h0.f[p]);
        float im1 = 0.33f * (l1.f[p] + m1.f[p] + h1.f[p]);
        float im2 = 0.33f * (l2.f[p] + m2.f[p] + h2.f[p]);
        float cf[12];
        #pragma unroll
        for (int qq = 0; qq < 3; ++qq) {
            #pragma unroll
            for (int r = 0; r < 4; ++r) {
                float a = first ? A0[qq].f[r] : B0[qq].f[r];
                float bb = first ? B0[qq].f[r] : C0[qq].f[r];
                cf[qq * 4 + r] = a + (bb - a) * fx;
            }
        }
        o0.f[p] = cf[0] * im0 + cf[1]  * im1 + cf[2]  * im2 + cf[3];
        o1.f[p] = cf[4] * im0 + cf[5]  * im1 + cf[6]  * im2 + cf[7];
        o2.f[p] = cf[8] * im0 + cf[9]  * im1 + cf[10] * im2 + cf[11];
    }
    float4* Op = (float4*)out;
    Op[g]           = o0.v;
    Op[g + HW4]     = o1.v;
    Op[g + 2 * HW4] = o2.v;
}

extern "C" void kernel_launch(void* const* d_in, const int* in_sizes, int n_in,
                              void* d_out, int out_size, void* d_ws, size_t ws_size,
                              hipStream_t stream) {
    const float* low   = (const float*)d_in[0];
    const float* med   = (const float*)d_in[1];
    const float* high  = (const float*)d_in[2];
    const float* w1    = (const float*)d_in[3];
    const float* b1    = (const float*)d_in[4];
    const float* w2    = (const float*)d_in[5];
    const float* b2    = (const float*)d_in[6];
    const float* w3    = (const float*)d_in[7];
    const float* b3    = (const float*)d_in[8];
    const float* w4    = (const float*)d_in[9];
    const float* b4    = (const float*)d_in[10];
    const float* gw1   = (const float*)d_in[11];
    const float* gb1   = (const float*)d_in[12];
    const float* gamma = (const float*)d_in[13];
    const float* beta  = (const float*)d_in[14];
    const float* mean  = (const float*)d_in[15];
    const float* var   = (const float*)d_in[16];
    const float* gw2   = (const float*)d_in[17];
    const float* gb2   = (const float*)d_in[18];
    float* out = (float*)d_out;

    float* ws      = (float*)d_ws;
    float* ab_full = ws;                    // 2048*768 = 1572864
    float* c1      = ab_full + 1572864;     // 16*64*64   =  65536
    float* c2v     = c1 + 65536;            // 32*32*32   =  32768
    float* gridvol = c2v + 32768;           // 192*16*16  =  49152
    float* guideb  = gridvol + 49152;       // 64*64      =   4096

    hipLaunchKernelGGL(k_conv1,    dim3(256), dim3(256), 0, stream,
                       low, med, high, w1, b1, c1);
    hipLaunchKernelGGL(k_conv2,    dim3(128), dim3(256), 0, stream,
                       c1, w2, b2, low, med, high,
                       gw1, gb1, gamma, beta, mean, var, gw2, gb2, c2v, guideb);
    hipLaunchKernelGGL(k_conv34,   dim3(64),  dim3(256), 0, stream, c2v, w3, b3, w4, b4, gridvol);
    hipLaunchKernelGGL(k_slice_ab, dim3(256), dim3(256), 0, stream, gridvol, guideb, ab_full);
    hipLaunchKernelGGL(k_apply,    dim3(4096), dim3(256), 0, stream, low, med, high, ab_full, out);
}